// Round 15
// baseline (1043.141 us; speedup 1.0000x reference)
//
#include <hip/hip_runtime.h>
#include <cstdint>
#include <cstddef>

#define E_TOT 131072
#define NNODES 8192

typedef __attribute__((ext_vector_type(8))) short bf16x8;
typedef __attribute__((ext_vector_type(4))) float f32x4;
typedef unsigned short u16;
typedef unsigned int u32;

__device__ __forceinline__ u16 f2bf(float f) {
    u32 u = __builtin_bit_cast(u32, f);
    u32 r = (u + 0x7FFFu + ((u >> 16) & 1u)) >> 16;
    return (u16)r;
}

// ---- weight convert + transpose: dst[n*K+k] = bf16(src[k*N+n]) ----
__global__ void wconv_kernel(const float* __restrict__ src, u16* __restrict__ dst,
                             int K, int N) {
    int idx = blockIdx.x * 256 + threadIdx.x;
    if (idx >= N * K) return;
    int n = idx / K, k = idx - n * K;
    dst[idx] = f2bf(src[(size_t)k * N + n]);
}

// ---- envelope(r) and Y = [1, sqrt3*nhat] per edge ----
__global__ void envy_kernel(const float* __restrict__ vectors, float* __restrict__ env,
                            float4* __restrict__ Y) {
    int e = blockIdx.x * 256 + threadIdx.x;
    float vx = vectors[3 * e + 0], vy = vectors[3 * e + 1], vz = vectors[3 * e + 2];
    float r2 = vx * vx + vy * vy + vz * vz;
    float r = sqrtf(r2);
    float u6 = r2 * r2 * r2;
    float f = 1.0f + u6 * (-28.0f + 48.0f * r - 21.0f * r2);
    env[e] = (r < 1.0f) ? f : 0.0f;
    float inv = 1.7320508075688772f / r;
    Y[e] = make_float4(1.0f, vx * inv, vy * inv, vz * inv);
}

// ---- counting sort: histogram ----
__global__ void hist_kernel(const int* __restrict__ senders, int* __restrict__ cnt) {
    int e = blockIdx.x * 256 + threadIdx.x;
    atomicAdd(&cnt[senders[e]], 1);
}

// ---- single-block exclusive scan of 8192 counts -> off[8193], curs[8192] ----
__launch_bounds__(1024)
__global__ void scan_kernel(const int* __restrict__ cnt, int* __restrict__ off,
                            int* __restrict__ curs) {
    __shared__ int part[1024];
    const int t = threadIdx.x;
    int local[8];
    int s = 0;
#pragma unroll
    for (int j = 0; j < 8; ++j) { local[j] = cnt[t * 8 + j]; s += local[j]; }
    part[t] = s;
    __syncthreads();
    for (int d = 1; d < 1024; d <<= 1) {
        int v = (t >= d) ? part[t - d] : 0;
        __syncthreads();
        part[t] += v;
        __syncthreads();
    }
    int run = part[t] - s; // exclusive base
#pragma unroll
    for (int j = 0; j < 8; ++j) {
        off[t * 8 + j] = run;
        curs[t * 8 + j] = run;
        run += local[j];
    }
    if (t == 1023) off[8192] = run;
}

// ---- perm build: perm[pos] = e ----
__global__ void permbuild_kernel(const int* __restrict__ senders, int* __restrict__ curs,
                                 int* __restrict__ perm) {
    int e = blockIdx.x * 256 + threadIdx.x;
    int s = senders[e];
    int p = atomicAdd(&curs[s], 1);
    perm[p] = e;
}

// ---- gather segment-sum: agg[n][m][:] = sum_{e in seg(n)} w[e][m]*Y[e] ----
__launch_bounds__(256)
__global__ void gather_kernel(const float* __restrict__ w, const float4* __restrict__ Y,
                              const int* __restrict__ off, const int* __restrict__ perm,
                              float4* __restrict__ agg) {
    const int t = threadIdx.x;
    const int n = blockIdx.x * 4 + (t >> 6);
    const int m = t & 63;
    const int beg = off[n], end = off[n + 1];
    float4 acc = make_float4(0.f, 0.f, 0.f, 0.f);
    for (int i = beg; i < end; ++i) {
        int e = perm[i];
        float wv = w[(size_t)e * 64 + m];
        float4 y = Y[e];
        acc.x += wv * y.x; acc.y += wv * y.y; acc.z += wv * y.z; acc.w += wv * y.w;
    }
    agg[(size_t)n * 64 + m] = acc;
}

// ---- fused: w = x @ W_w / sqrt(512) AND XB = bf16(x) ----
__launch_bounds__(256)
__global__ void wgemm_kernel(const float* __restrict__ x, const u16* __restrict__ Wt,
                             u16* __restrict__ XB, float* __restrict__ w) {
    __shared__ u16 As[128 * 72];
    __shared__ u16 Bs[64 * 72];
    const int e0 = blockIdx.x * 128;
    const int t = threadIdx.x, lane = t & 63, wid = t >> 6;
    const int lr = lane & 15, lh = lane >> 4;
    const int r8 = t >> 3, c8 = t & 7;
    f32x4 acc[2][4] = {};
    for (int kt = 0; kt < 8; ++kt) {
        const int kk = kt << 6;
#pragma unroll
        for (int i = 0; i < 4; ++i) {
            int row = i * 32 + r8;
            const float* gx = x + (size_t)(e0 + row) * 512 + kk + c8 * 8;
            float4 a = *(const float4*)gx;
            float4 b = *(const float4*)(gx + 4);
            union { u16 h[8]; uint4 v; } p;
            p.h[0] = f2bf(a.x); p.h[1] = f2bf(a.y); p.h[2] = f2bf(a.z); p.h[3] = f2bf(a.w);
            p.h[4] = f2bf(b.x); p.h[5] = f2bf(b.y); p.h[6] = f2bf(b.z); p.h[7] = f2bf(b.w);
            *(uint4*)((char*)As + row * 144 + c8 * 16) = p.v;
            *(uint4*)(XB + (size_t)(e0 + row) * 512 + kk + c8 * 8) = p.v;
        }
#pragma unroll
        for (int i = 0; i < 2; ++i) {
            int row = i * 32 + r8;
            const u16* g = Wt + (size_t)row * 512 + kk + c8 * 8;
            *(uint4*)((char*)Bs + row * 144 + c8 * 16) = *(const uint4*)g;
        }
        __syncthreads();
#pragma unroll
        for (int k2 = 0; k2 < 2; ++k2) {
            bf16x8 af[2], bfr[4];
#pragma unroll
            for (int m = 0; m < 2; ++m)
                af[m] = *(const bf16x8*)((const char*)As + (wid * 32 + m * 16 + lr) * 144 + k2 * 64 + lh * 16);
#pragma unroll
            for (int n = 0; n < 4; ++n)
                bfr[n] = *(const bf16x8*)((const char*)Bs + (n * 16 + lr) * 144 + k2 * 64 + lh * 16);
#pragma unroll
            for (int m = 0; m < 2; ++m)
#pragma unroll
                for (int n = 0; n < 4; ++n)
                    acc[m][n] = __builtin_amdgcn_mfma_f32_16x16x32_bf16(af[m], bfr[n], acc[m][n], 0, 0, 0);
        }
        __syncthreads();
    }
    const float s = 0.044194173824159216f; // 1/sqrt(512)
#pragma unroll
    for (int m = 0; m < 2; ++m)
#pragma unroll
        for (int n = 0; n < 4; ++n)
#pragma unroll
            for (int j = 0; j < 4; ++j) {
                int e = e0 + wid * 32 + m * 16 + lh * 4 + j;
                w[(size_t)e * 64 + n * 16 + lr] = acc[m][n][j] * s;
            }
}

// ---- edge products: scal (bf16) + fused V_out GEMM (K=192) ----
__launch_bounds__(256)
__global__ void edge_kernel(const int* __restrict__ senders, const float4* __restrict__ agg4,
                            const float4* __restrict__ V4, const u16* __restrict__ Wlt,
                            u16* __restrict__ scal, float* __restrict__ Vout) {
    __shared__ u16 a_lds[3][32][200];
    __shared__ u16 w_lds[64 * 200];
    const int t = threadIdx.x;
    const int e0 = blockIdx.x * 32;
#pragma unroll
    for (int i = 0; i < 6; ++i) {
        int c = i * 256 + t;
        int row = c / 24, off = (c % 24) * 8;
        *(uint4*)((char*)w_lds + row * 400 + off * 2) = ((const uint4*)Wlt)[c];
    }
    const float invs3 = 0.5773502691896258f;
    const float invs2 = 0.7071067811865476f;
    const float EPS = 0.24253562503633297f;
#pragma unroll
    for (int i = 0; i < 8; ++i) {
        int el = i * 4 + (t >> 6);
        int m = t & 63;
        int e = e0 + el;
        int s = senders[e];
        float4 a = agg4[(size_t)s * 64 + m];
        a.x *= EPS; a.y *= EPS; a.z *= EPS; a.w *= EPS;
        float4 b = V4[(size_t)e * 64 + m];
        float s0 = a.x * b.x;
        float s1 = (a.y * b.y + a.z * b.z + a.w * b.w) * invs3;
        scal[(size_t)e * 128 + m] = f2bf(s0);
        scal[(size_t)e * 128 + 64 + m] = f2bf(s1);
        float cx = (a.z * b.w - a.w * b.z) * invs2;
        float cy = (a.w * b.y - a.y * b.w) * invs2;
        float cz = (a.y * b.z - a.z * b.y) * invs2;
        a_lds[0][el][m] = f2bf(a.x * b.y);
        a_lds[0][el][64 + m] = f2bf(a.y * b.x);
        a_lds[0][el][128 + m] = f2bf(cx);
        a_lds[1][el][m] = f2bf(a.x * b.z);
        a_lds[1][el][64 + m] = f2bf(a.z * b.x);
        a_lds[1][el][128 + m] = f2bf(cy);
        a_lds[2][el][m] = f2bf(a.x * b.w);
        a_lds[2][el][64 + m] = f2bf(a.w * b.x);
        a_lds[2][el][128 + m] = f2bf(cz);
    }
    __syncthreads();
    const int lane = t & 63, wid = t >> 6;
    const int lr = lane & 15, lh = lane >> 4;
    f32x4 acc[3][2] = {};
    for (int kt = 0; kt < 6; ++kt) {
        bf16x8 bfr = *(const bf16x8*)((const char*)w_lds + (wid * 16 + lr) * 400 + kt * 64 + lh * 16);
#pragma unroll
        for (int c = 0; c < 3; ++c)
#pragma unroll
            for (int m = 0; m < 2; ++m) {
                bf16x8 afr = *(const bf16x8*)((const char*)a_lds + ((c * 32 + m * 16 + lr) * 400) + kt * 64 + lh * 16);
                acc[c][m] = __builtin_amdgcn_mfma_f32_16x16x32_bf16(afr, bfr, acc[c][m], 0, 0, 0);
            }
    }
    __syncthreads();
    float* ot = (float*)a_lds;
    const float sc = 0.07216878364870323f; // 1/sqrt(192)
#pragma unroll
    for (int c = 0; c < 3; ++c)
#pragma unroll
        for (int m = 0; m < 2; ++m)
#pragma unroll
            for (int j = 0; j < 4; ++j) {
                int row = m * 16 + lh * 4 + j;
                int mul = wid * 16 + lr;
                ot[row * 192 + mul * 3 + c] = acc[c][m][j] * sc;
            }
    __syncthreads();
    float4* vo = (float4*)(Vout + (size_t)e0 * 192);
#pragma unroll
    for (int i = 0; i < 6; ++i)
        vo[i * 256 + t] = ((float4*)ot)[i * 256 + t];
}

// ---- MLP GEMM v8: LDS-FREE. Each wave independently computes a 64x64
//      output tile, A and B fragments loaded straight from global into
//      registers (B panels are permanently L2-resident; A rows are read
//      K-contiguously = fragment layout). No barriers, no LDS, no vmcnt.
//      Register double-buffer with NAMED buffers (2-step unroll, rule #20).
//      Line-utilization: per frag-load 16 lr-lanes x 4 lh-slots = 16 full
//      64B lines, zero over-fetch. nt-inner wave order: A strip shared by
//      8 consecutive waves (L1/L2 hits). 12 waves/CU.
//      MODE 0: silu->bf16, MODE 1: env-scale->f32.
template <int MODE, int K>
__launch_bounds__(256, 3)
__global__ void mlp_gemm(const u16* __restrict__ A, const u16* __restrict__ A2,
                         const u16* __restrict__ Bt, const float scale,
                         const float* __restrict__ env,
                         u16* __restrict__ outb, float* __restrict__ outf) {
    constexpr int NKT = K >> 5;            // K-steps of 32
    const int nwg = gridDim.x;             // 4096, %8==0
    const int bid = blockIdx.x;
    const int swz = (bid & 7) * (nwg >> 3) + (bid >> 3); // bijective XCD swizzle
    const int t = threadIdx.x, lane = t & 63, wid = t >> 6;
    const int gw = swz * 4 + wid;          // global wave id
    const int ntile = gw & 7, mtile = gw >> 3;  // nt inner: A-strip shared
    const int e0 = mtile << 6, n0 = ntile << 6;
    const int lr = lane & 15, lh = lane >> 4;
    f32x4 acc[4][4] = {};

    bf16x8 a0[4], b0[4], a1[4], b1[4];

    auto loadA = [&](bf16x8* d, int kk) {
#pragma unroll
        for (int fi = 0; fi < 4; ++fi) {
            const u16* p;
            if (A2 && kk >= 512) p = A2 + (size_t)(e0 + fi * 16 + lr) * 128 + (kk - 512) + lh * 8;
            else                 p = A + (size_t)(e0 + fi * 16 + lr) * 512 + kk + lh * 8;
            d[fi] = *(const bf16x8*)p;
        }
    };
    auto loadB = [&](bf16x8* d, int kk) {
#pragma unroll
        for (int nf = 0; nf < 4; ++nf)
            d[nf] = *(const bf16x8*)(Bt + (size_t)(n0 + nf * 16 + lr) * K + kk + lh * 8);
    };
    auto mfma16 = [&](const bf16x8* af, const bf16x8* bfr) {
#pragma unroll
        for (int fi = 0; fi < 4; ++fi)
#pragma unroll
            for (int nf = 0; nf < 4; ++nf)
                acc[fi][nf] = __builtin_amdgcn_mfma_f32_16x16x32_bf16(af[fi], bfr[nf], acc[fi][nf], 0, 0, 0);
    };

    loadA(a0, 0); loadB(b0, 0);
#pragma unroll 1
    for (int kt = 0; kt < NKT; kt += 2) {
        if (kt + 1 < NKT) { loadA(a1, (kt + 1) << 5); loadB(b1, (kt + 1) << 5); }
        mfma16(a0, b0);
        if (kt + 2 < NKT) { loadA(a0, (kt + 2) << 5); loadB(b0, (kt + 2) << 5); }
        if (kt + 1 < NKT) mfma16(a1, b1);
    }

    // epilogue: per-wave 64x64 tile, 16-contiguous-lane stores
#pragma unroll
    for (int fi = 0; fi < 4; ++fi) {
#pragma unroll
        for (int j = 0; j < 4; ++j) {
            const int row = e0 + fi * 16 + lh * 4 + j;
            float ev = (MODE == 1) ? env[row] : 0.0f;
#pragma unroll
            for (int nf = 0; nf < 4; ++nf) {
                const int col = n0 + nf * 16 + lr;
                float v = acc[fi][nf][j] * scale;
                if (MODE == 0) {
                    float sv = v / (1.0f + __expf(-v));
                    outb[(size_t)row * 512 + col] = f2bf(sv);
                } else {
                    outf[(size_t)row * 512 + col] = v * ev;
                }
            }
        }
    }
}

extern "C" void kernel_launch(void* const* d_in, const int* in_sizes, int n_in,
                              void* d_out, int out_size, void* d_ws, size_t ws_size,
                              hipStream_t stream) {
    const float* vectors = (const float*)d_in[0];
    const float* x       = (const float*)d_in[1];
    const float* V       = (const float*)d_in[2];
    const int*   senders = (const int*)d_in[3];
    const float* W_w     = (const float*)d_in[4];
    const float* W1      = (const float*)d_in[5];
    const float* W2      = (const float*)d_in[6];
    const float* W3      = (const float*)d_in[7];
    const float* W_lin   = (const float*)d_in[8];
    float* out = (float*)d_out;
    char* ws = (char*)d_ws;

    u16*    XB   = (u16*)(ws + 0x0);          // E*512 bf16
    u16*    H1   = (u16*)(ws + 0x8000000);    // E*512 bf16
    u16*    SCAL = (u16*)(ws + 0x10000000);   // E*128 bf16
    float*  AGG  = (float*)(ws + 0x12000000); // 8192*256 f32
    float*  ENV  = (float*)(ws + 0x12800000); // E f32
    float4* Yb   = (float4*)(ws + 0x12880000);// E float4
    float*  Wbuf = (float*)(ws + 0x12A80000); // E*64 f32
    u16*    WT   = (u16*)(ws + 0x14A80000);   // weights bf16
    u16* Wwt = WT;                 // 64 x 512
    u16* W1t = Wwt + 64 * 512;     // 512 x 640
    u16* W2t = W1t + 512 * 640;    // 512 x 512
    u16* W3t = W2t + 512 * 512;    // 512 x 512
    u16* Wlt = W3t + 512 * 512;    // 64 x 192
    u16* H2 = XB;                  // reuse XB for h2 (GEMM1 done reading by then)
    // sort scratch
    int* COUNT = (int*)(ws + 0x15000000);     // 8192
    int* OFF   = (int*)(ws + 0x15010000);     // 8193
    int* CURS  = (int*)(ws + 0x15020000);     // 8192
    int* PERM  = (int*)(ws + 0x15030000);     // E

    hipMemsetAsync(COUNT, 0, NNODES * sizeof(int), stream);

    wconv_kernel<<<(64 * 512) / 256, 256, 0, stream>>>(W_w, Wwt, 512, 64);
    wconv_kernel<<<(512 * 640) / 256, 256, 0, stream>>>(W1, W1t, 640, 512);
    wconv_kernel<<<(512 * 512) / 256, 256, 0, stream>>>(W2, W2t, 512, 512);
    wconv_kernel<<<(512 * 512) / 256, 256, 0, stream>>>(W3, W3t, 512, 512);
    wconv_kernel<<<(64 * 192) / 256, 256, 0, stream>>>(W_lin, Wlt, 192, 64);

    envy_kernel<<<E_TOT / 256, 256, 0, stream>>>(vectors, ENV, Yb);

    hist_kernel<<<E_TOT / 256, 256, 0, stream>>>(senders, COUNT);
    scan_kernel<<<1, 1024, 0, stream>>>(COUNT, OFF, CURS);
    permbuild_kernel<<<E_TOT / 256, 256, 0, stream>>>(senders, CURS, PERM);

    // fused x->bf16 conversion + w-GEMM
    wgemm_kernel<<<E_TOT / 128, 256, 0, stream>>>(x, Wwt, XB, Wbuf);
    gather_kernel<<<NNODES / 4, 256, 0, stream>>>(Wbuf, Yb, OFF, PERM, (float4*)AGG);

    edge_kernel<<<E_TOT / 32, 256, 0, stream>>>(senders, (const float4*)AGG, (const float4*)V,
                                                Wlt, SCAL, out + (size_t)E_TOT * 512);

    const float s640 = 0.03952847075210474f;  // 1/sqrt(640)
    const float s512 = 0.044194173824159216f; // 1/sqrt(512)
    // LDS-free GEMM: 2048 mt x 8 nt = 16384 wave-tiles / 4 waves = 4096 blocks
    const int gemm_grid = (E_TOT / 64) * 8 / 4;
    mlp_gemm<0, 640><<<gemm_grid, 256, 0, stream>>>(XB, SCAL, W1t, s640, nullptr, H1, nullptr);
    mlp_gemm<0, 512><<<gemm_grid, 256, 0, stream>>>(H1, nullptr, W2t, s512, nullptr, H2, nullptr);
    mlp_gemm<1, 512><<<gemm_grid, 256, 0, stream>>>(H2, nullptr, W3t, s512, ENV, nullptr, out);
}

// Round 16
// 572.176 us; speedup vs baseline: 1.8231x; 1.8231x over previous
//
#include <hip/hip_runtime.h>
#include <cstdint>
#include <cstddef>

#define E_TOT 131072
#define NNODES 8192

typedef __attribute__((ext_vector_type(8))) short bf16x8;
typedef __attribute__((ext_vector_type(4))) float f32x4;
typedef unsigned short u16;
typedef unsigned int u32;

__device__ __forceinline__ u16 f2bf(float f) {
    u32 u = __builtin_bit_cast(u32, f);
    u32 r = (u + 0x7FFFu + ((u >> 16) & 1u)) >> 16;
    return (u16)r;
}

__device__ __forceinline__ void gload16(const u16* g, u16* l) {
    __builtin_amdgcn_global_load_lds((const __attribute__((address_space(1))) void*)g,
                                     (__attribute__((address_space(3))) void*)l, 16, 0, 0);
}

// swizzled LDS fragment read: rows 128 B; byte col XORed with (row&7)<<4
__device__ __forceinline__ bf16x8 lds_frag(const u16* base, int row, int bytecol) {
    return *(const bf16x8*)((const char*)base + row * 128 + (bytecol ^ ((row & 7) << 4)));
}

// ---- weight convert + transpose: dst[n*K+k] = bf16(src[k*N+n]) ----
__global__ void wconv_kernel(const float* __restrict__ src, u16* __restrict__ dst,
                             int K, int N) {
    int idx = blockIdx.x * 256 + threadIdx.x;
    if (idx >= N * K) return;
    int n = idx / K, k = idx - n * K;
    dst[idx] = f2bf(src[(size_t)k * N + n]);
}

// ---- envelope(r) and Y = [1, sqrt3*nhat] per edge ----
__global__ void envy_kernel(const float* __restrict__ vectors, float* __restrict__ env,
                            float4* __restrict__ Y) {
    int e = blockIdx.x * 256 + threadIdx.x;
    float vx = vectors[3 * e + 0], vy = vectors[3 * e + 1], vz = vectors[3 * e + 2];
    float r2 = vx * vx + vy * vy + vz * vz;
    float r = sqrtf(r2);
    float u6 = r2 * r2 * r2;
    float f = 1.0f + u6 * (-28.0f + 48.0f * r - 21.0f * r2);
    env[e] = (r < 1.0f) ? f : 0.0f;
    float inv = 1.7320508075688772f / r;
    Y[e] = make_float4(1.0f, vx * inv, vy * inv, vz * inv);
}

// ---- counting sort: histogram ----
__global__ void hist_kernel(const int* __restrict__ senders, int* __restrict__ cnt) {
    int e = blockIdx.x * 256 + threadIdx.x;
    atomicAdd(&cnt[senders[e]], 1);
}

// ---- single-block exclusive scan of 8192 counts -> off[8193], curs[8192] ----
__launch_bounds__(1024)
__global__ void scan_kernel(const int* __restrict__ cnt, int* __restrict__ off,
                            int* __restrict__ curs) {
    __shared__ int part[1024];
    const int t = threadIdx.x;
    int local[8];
    int s = 0;
#pragma unroll
    for (int j = 0; j < 8; ++j) { local[j] = cnt[t * 8 + j]; s += local[j]; }
    part[t] = s;
    __syncthreads();
    for (int d = 1; d < 1024; d <<= 1) {
        int v = (t >= d) ? part[t - d] : 0;
        __syncthreads();
        part[t] += v;
        __syncthreads();
    }
    int run = part[t] - s; // exclusive base
#pragma unroll
    for (int j = 0; j < 8; ++j) {
        off[t * 8 + j] = run;
        curs[t * 8 + j] = run;
        run += local[j];
    }
    if (t == 1023) off[8192] = run;
}

// ---- perm build: perm[pos] = e ----
__global__ void permbuild_kernel(const int* __restrict__ senders, int* __restrict__ curs,
                                 int* __restrict__ perm) {
    int e = blockIdx.x * 256 + threadIdx.x;
    int s = senders[e];
    int p = atomicAdd(&curs[s], 1);
    perm[p] = e;
}

// ---- gather segment-sum: agg[n][m][:] = sum_{e in seg(n)} w[e][m]*Y[e] ----
__launch_bounds__(256)
__global__ void gather_kernel(const float* __restrict__ w, const float4* __restrict__ Y,
                              const int* __restrict__ off, const int* __restrict__ perm,
                              float4* __restrict__ agg) {
    const int t = threadIdx.x;
    const int n = blockIdx.x * 4 + (t >> 6);
    const int m = t & 63;
    const int beg = off[n], end = off[n + 1];
    float4 acc = make_float4(0.f, 0.f, 0.f, 0.f);
    for (int i = beg; i < end; ++i) {
        int e = perm[i];
        float wv = w[(size_t)e * 64 + m];
        float4 y = Y[e];
        acc.x += wv * y.x; acc.y += wv * y.y; acc.z += wv * y.z; acc.w += wv * y.w;
    }
    agg[(size_t)n * 64 + m] = acc;
}

// ---- fused: w = x @ W_w / sqrt(512) AND XB = bf16(x), XB in K-TILED layout
//      XB[(kt*E + e)*64 + (k&63)] — each GEMM K-step reads contiguous 32 KB.
__launch_bounds__(256)
__global__ void wgemm_kernel(const float* __restrict__ x, const u16* __restrict__ Wt,
                             u16* __restrict__ XB, float* __restrict__ w) {
    __shared__ u16 As[128 * 72];
    __shared__ u16 Bs[64 * 72];
    const int e0 = blockIdx.x * 128;
    const int t = threadIdx.x, lane = t & 63, wid = t >> 6;
    const int lr = lane & 15, lh = lane >> 4;
    const int r8 = t >> 3, c8 = t & 7;
    f32x4 acc[2][4] = {};
    for (int kt = 0; kt < 8; ++kt) {
        const int kk = kt << 6;
#pragma unroll
        for (int i = 0; i < 4; ++i) {
            int row = i * 32 + r8;
            const float* gx = x + (size_t)(e0 + row) * 512 + kk + c8 * 8;
            float4 a = *(const float4*)gx;
            float4 b = *(const float4*)(gx + 4);
            union { u16 h[8]; uint4 v; } p;
            p.h[0] = f2bf(a.x); p.h[1] = f2bf(a.y); p.h[2] = f2bf(a.z); p.h[3] = f2bf(a.w);
            p.h[4] = f2bf(b.x); p.h[5] = f2bf(b.y); p.h[6] = f2bf(b.z); p.h[7] = f2bf(b.w);
            *(uint4*)((char*)As + row * 144 + c8 * 16) = p.v;
            // K-tiled store: tile kt, row e0+row, col c8*8
            *(uint4*)(XB + ((size_t)kt * E_TOT + e0 + row) * 64 + c8 * 8) = p.v;
        }
#pragma unroll
        for (int i = 0; i < 2; ++i) {
            int row = i * 32 + r8;
            const u16* g = Wt + (size_t)row * 512 + kk + c8 * 8;
            *(uint4*)((char*)Bs + row * 144 + c8 * 16) = *(const uint4*)g;
        }
        __syncthreads();
#pragma unroll
        for (int k2 = 0; k2 < 2; ++k2) {
            bf16x8 af[2], bfr[4];
#pragma unroll
            for (int m = 0; m < 2; ++m)
                af[m] = *(const bf16x8*)((const char*)As + (wid * 32 + m * 16 + lr) * 144 + k2 * 64 + lh * 16);
#pragma unroll
            for (int n = 0; n < 4; ++n)
                bfr[n] = *(const bf16x8*)((const char*)Bs + (n * 16 + lr) * 144 + k2 * 64 + lh * 16);
#pragma unroll
            for (int m = 0; m < 2; ++m)
#pragma unroll
                for (int n = 0; n < 4; ++n)
                    acc[m][n] = __builtin_amdgcn_mfma_f32_16x16x32_bf16(af[m], bfr[n], acc[m][n], 0, 0, 0);
        }
        __syncthreads();
    }
    const float s = 0.044194173824159216f; // 1/sqrt(512)
#pragma unroll
    for (int m = 0; m < 2; ++m)
#pragma unroll
        for (int n = 0; n < 4; ++n)
#pragma unroll
            for (int j = 0; j < 4; ++j) {
                int e = e0 + wid * 32 + m * 16 + lh * 4 + j;
                w[(size_t)e * 64 + n * 16 + lr] = acc[m][n][j] * s;
            }
}

// ---- edge products: scal (bf16, K-TILED: 2 tiles of [E][64]) + V_out GEMM ----
__launch_bounds__(256)
__global__ void edge_kernel(const int* __restrict__ senders, const float4* __restrict__ agg4,
                            const float4* __restrict__ V4, const u16* __restrict__ Wlt,
                            u16* __restrict__ scal, float* __restrict__ Vout) {
    __shared__ u16 a_lds[3][32][200];
    __shared__ u16 w_lds[64 * 200];
    const int t = threadIdx.x;
    const int e0 = blockIdx.x * 32;
#pragma unroll
    for (int i = 0; i < 6; ++i) {
        int c = i * 256 + t;
        int row = c / 24, off = (c % 24) * 8;
        *(uint4*)((char*)w_lds + row * 400 + off * 2) = ((const uint4*)Wlt)[c];
    }
    const float invs3 = 0.5773502691896258f;
    const float invs2 = 0.7071067811865476f;
    const float EPS = 0.24253562503633297f;
#pragma unroll
    for (int i = 0; i < 8; ++i) {
        int el = i * 4 + (t >> 6);
        int m = t & 63;
        int e = e0 + el;
        int s = senders[e];
        float4 a = agg4[(size_t)s * 64 + m];
        a.x *= EPS; a.y *= EPS; a.z *= EPS; a.w *= EPS;
        float4 b = V4[(size_t)e * 64 + m];
        float s0 = a.x * b.x;
        float s1 = (a.y * b.y + a.z * b.z + a.w * b.w) * invs3;
        scal[(size_t)e * 64 + m] = f2bf(s0);                       // K-tile 0
        scal[(size_t)E_TOT * 64 + (size_t)e * 64 + m] = f2bf(s1);  // K-tile 1
        float cx = (a.z * b.w - a.w * b.z) * invs2;
        float cy = (a.w * b.y - a.y * b.w) * invs2;
        float cz = (a.y * b.z - a.z * b.y) * invs2;
        a_lds[0][el][m] = f2bf(a.x * b.y);
        a_lds[0][el][64 + m] = f2bf(a.y * b.x);
        a_lds[0][el][128 + m] = f2bf(cx);
        a_lds[1][el][m] = f2bf(a.x * b.z);
        a_lds[1][el][64 + m] = f2bf(a.z * b.x);
        a_lds[1][el][128 + m] = f2bf(cy);
        a_lds[2][el][m] = f2bf(a.x * b.w);
        a_lds[2][el][64 + m] = f2bf(a.w * b.x);
        a_lds[2][el][128 + m] = f2bf(cz);
    }
    __syncthreads();
    const int lane = t & 63, wid = t >> 6;
    const int lr = lane & 15, lh = lane >> 4;
    f32x4 acc[3][2] = {};
    for (int kt = 0; kt < 6; ++kt) {
        bf16x8 bfr = *(const bf16x8*)((const char*)w_lds + (wid * 16 + lr) * 400 + kt * 64 + lh * 16);
#pragma unroll
        for (int c = 0; c < 3; ++c)
#pragma unroll
            for (int m = 0; m < 2; ++m) {
                bf16x8 afr = *(const bf16x8*)((const char*)a_lds + ((c * 32 + m * 16 + lr) * 400) + kt * 64 + lh * 16);
                acc[c][m] = __builtin_amdgcn_mfma_f32_16x16x32_bf16(afr, bfr, acc[c][m], 0, 0, 0);
            }
    }
    __syncthreads();
    float* ot = (float*)a_lds;
    const float sc = 0.07216878364870323f; // 1/sqrt(192)
#pragma unroll
    for (int c = 0; c < 3; ++c)
#pragma unroll
        for (int m = 0; m < 2; ++m)
#pragma unroll
            for (int j = 0; j < 4; ++j) {
                int row = m * 16 + lh * 4 + j;
                int mul = wid * 16 + lr;
                ot[row * 192 + mul * 3 + c] = acc[c][m][j] * sc;
            }
    __syncthreads();
    float4* vo = (float4*)(Vout + (size_t)e0 * 192);
#pragma unroll
    for (int i = 0; i < 6; ++i)
        vo[i * 256 + t] = ((float4*)ot)[i * 256 + t];
}

// ---- MLP GEMM v9: r14 structure (persistent 256², 16 waves, counted vmcnt)
//      with K-TILED activations: A[(ktile*E + row)*64 + col] — each K-step's
//      A-fetch is one CONTIGUOUS 32 KB block (vs 256 strided 128 B granules).
//      MODE 0 writes K-tiled bf16; MODE 1 writes row-major f32 (final out).
//      vmcnt audit unchanged from r14 (addresses only).
template <int MODE, int K>
__launch_bounds__(1024)
__global__ void mlp_gemm(const u16* __restrict__ A, const u16* __restrict__ A2,
                         const u16* __restrict__ Bt, const float scale,
                         const float* __restrict__ env,
                         u16* __restrict__ outb, float* __restrict__ outf) {
    constexpr int NKT = K >> 6;
    constexpr int NSTEP = NKT * 4; // 4 tiles per block
    __shared__ u16 lds[2][2][256 * 64]; // [dbuf][A/B][row*64+col], 128 KiB
    const int b = blockIdx.x; // 0..255
    const int t = threadIdx.x, lane = t & 63, wid = t >> 6;
    const int wm = wid >> 2, wn = wid & 3;  // 4 x 4 wave grid, wave-tile 64x64
    const int lr = lane & 15, lh = lane >> 4;
    f32x4 acc[4][4] = {};

    auto issue = [&](int g) {
        const int tile = g / NKT;
        const int kt = g - tile * NKT;
        const int tid = b * 4 + tile;       // nt inner: (mt,0),(mt,1),(mt+1,0),...
        const int e0 = (tid >> 1) << 8;
        const int n0 = (tid & 1) << 8;
        const int kk = kt << 6;
        const int buf = g & 1;
        // A (K-tiled): contiguous 32 KB block per step
        const u16* abase;
        size_t arow;
        if (A2 && kk >= 512) { abase = A2; arow = (size_t)((kk - 512) >> 6) * E_TOT + e0; }
        else                 { abase = A;  arow = (size_t)(kk >> 6) * E_TOT + e0; }
#pragma unroll
        for (int i = 0; i < 2; ++i) {
            const int c = i * 1024 + t;
            const int rowin = c >> 3;
            const int scol = ((c & 7) ^ (rowin & 7)) << 3;
            gload16(abase + (arow + rowin) * 64 + scol,
                    (u16*)&lds[buf][0][0] + (size_t)c * 8);
        }
#pragma unroll
        for (int i = 0; i < 2; ++i) {
            const int c = i * 1024 + t;
            const int rowin = c >> 3;
            const int scol = ((c & 7) ^ (rowin & 7)) << 3;
            gload16(Bt + (size_t)(n0 + rowin) * K + kk + scol,
                    (u16*)&lds[buf][1][0] + (size_t)c * 8);
        }
    };

    issue(0);
    issue(1);
    for (int g = 0; g < NSTEP; ++g) {
        const int tile = g / NKT;
        const int kt = g - tile * NKT;
        // fused wait+barrier (one asm unit) — r14 audit
        if (g + 1 >= NSTEP)           asm volatile("s_waitcnt vmcnt(0)\ns_barrier" ::: "memory");
        else if (kt <= 1 && tile > 0) asm volatile("s_waitcnt vmcnt(8)\ns_barrier" ::: "memory");
        else                          asm volatile("s_waitcnt vmcnt(4)\ns_barrier" ::: "memory");
        const u16* Ab = lds[g & 1][0];
        const u16* Bb = lds[g & 1][1];
        __builtin_amdgcn_s_setprio(1);
#pragma unroll
        for (int k2 = 0; k2 < 2; ++k2) {
            bf16x8 af[4], bfr[4];
#pragma unroll
            for (int m = 0; m < 4; ++m)
                af[m] = lds_frag(Ab, wm * 64 + m * 16 + lr, k2 * 64 + lh * 16);
#pragma unroll
            for (int n = 0; n < 4; ++n)
                bfr[n] = lds_frag(Bb, wn * 64 + n * 16 + lr, k2 * 64 + lh * 16);
#pragma unroll
            for (int m = 0; m < 4; ++m)
#pragma unroll
                for (int n = 0; n < 4; ++n)
                    acc[m][n] = __builtin_amdgcn_mfma_f32_16x16x32_bf16(af[m], bfr[n], acc[m][n], 0, 0, 0);
        }
        __builtin_amdgcn_s_setprio(0);
        // all waves' reads of this buffer done -> safe to refill it
        asm volatile("s_waitcnt lgkmcnt(0)\ns_barrier" ::: "memory");
        if (g + 2 < NSTEP) issue(g + 2);
        if (kt == NKT - 1) {
            // epilogue for `tile` (overlaps next tile's in-flight loads)
            const int tid = b * 4 + tile;
            const int e0 = (tid >> 1) << 8;
            const int n0 = (tid & 1) << 8;
#pragma unroll
            for (int m = 0; m < 4; ++m) {
#pragma unroll
                for (int j = 0; j < 4; ++j) {
                    const int row = e0 + wm * 64 + m * 16 + lh * 4 + j;
                    float ev = (MODE == 1) ? env[row] : 0.0f;
#pragma unroll
                    for (int n = 0; n < 4; ++n) {
                        const int col = n0 + wn * 64 + n * 16 + lr;
                        float v = acc[m][n][j] * scale;
                        if (MODE == 0) {
                            float sv = v / (1.0f + __expf(-v));
                            // K-tiled store
                            outb[((size_t)(col >> 6) * E_TOT + row) * 64 + (col & 63)] = f2bf(sv);
                        } else {
                            outf[(size_t)row * 512 + col] = v * ev;
                        }
                    }
                }
            }
#pragma unroll
            for (int m = 0; m < 4; ++m)
#pragma unroll
                for (int n = 0; n < 4; ++n)
                    acc[m][n] = f32x4{0.f, 0.f, 0.f, 0.f};
        }
    }
}

extern "C" void kernel_launch(void* const* d_in, const int* in_sizes, int n_in,
                              void* d_out, int out_size, void* d_ws, size_t ws_size,
                              hipStream_t stream) {
    const float* vectors = (const float*)d_in[0];
    const float* x       = (const float*)d_in[1];
    const float* V       = (const float*)d_in[2];
    const int*   senders = (const int*)d_in[3];
    const float* W_w     = (const float*)d_in[4];
    const float* W1      = (const float*)d_in[5];
    const float* W2      = (const float*)d_in[6];
    const float* W3      = (const float*)d_in[7];
    const float* W_lin   = (const float*)d_in[8];
    float* out = (float*)d_out;
    char* ws = (char*)d_ws;

    u16*    XB   = (u16*)(ws + 0x0);          // E*512 bf16 (K-tiled [8][E][64])
    u16*    H1   = (u16*)(ws + 0x8000000);    // E*512 bf16 (K-tiled)
    u16*    SCAL = (u16*)(ws + 0x10000000);   // E*128 bf16 (K-tiled [2][E][64])
    float*  AGG  = (float*)(ws + 0x12000000); // 8192*256 f32
    float*  ENV  = (float*)(ws + 0x12800000); // E f32
    float4* Yb   = (float4*)(ws + 0x12880000);// E float4
    float*  Wbuf = (float*)(ws + 0x12A80000); // E*64 f32
    u16*    WT   = (u16*)(ws + 0x14A80000);   // weights bf16
    u16* Wwt = WT;                 // 64 x 512
    u16* W1t = Wwt + 64 * 512;     // 512 x 640
    u16* W2t = W1t + 512 * 640;    // 512 x 512
    u16* W3t = W2t + 512 * 512;    // 512 x 512
    u16* Wlt = W3t + 512 * 512;    // 64 x 192
    u16* H2 = XB;                  // reuse XB for h2 (K-tiled; GEMM1 done reading)
    // sort scratch
    int* COUNT = (int*)(ws + 0x15000000);     // 8192
    int* OFF   = (int*)(ws + 0x15010000);     // 8193
    int* CURS  = (int*)(ws + 0x15020000);     // 8192
    int* PERM  = (int*)(ws + 0x15030000);     // E

    hipMemsetAsync(COUNT, 0, NNODES * sizeof(int), stream);

    wconv_kernel<<<(64 * 512) / 256, 256, 0, stream>>>(W_w, Wwt, 512, 64);
    wconv_kernel<<<(512 * 640) / 256, 256, 0, stream>>>(W1, W1t, 640, 512);
    wconv_kernel<<<(512 * 512) / 256, 256, 0, stream>>>(W2, W2t, 512, 512);
    wconv_kernel<<<(512 * 512) / 256, 256, 0, stream>>>(W3, W3t, 512, 512);
    wconv_kernel<<<(64 * 192) / 256, 256, 0, stream>>>(W_lin, Wlt, 192, 64);

    envy_kernel<<<E_TOT / 256, 256, 0, stream>>>(vectors, ENV, Yb);

    hist_kernel<<<E_TOT / 256, 256, 0, stream>>>(senders, COUNT);
    scan_kernel<<<1, 1024, 0, stream>>>(COUNT, OFF, CURS);
    permbuild_kernel<<<E_TOT / 256, 256, 0, stream>>>(senders, CURS, PERM);

    // fused x->bf16 conversion (K-tiled XB) + w-GEMM
    wgemm_kernel<<<E_TOT / 128, 256, 0, stream>>>(x, Wwt, XB, Wbuf);
    gather_kernel<<<NNODES / 4, 256, 0, stream>>>(Wbuf, Yb, OFF, PERM, (float4*)AGG);

    edge_kernel<<<E_TOT / 32, 256, 0, stream>>>(senders, (const float4*)AGG, (const float4*)V,
                                                Wlt, SCAL, out + (size_t)E_TOT * 512);

    const float s640 = 0.03952847075210474f;  // 1/sqrt(640)
    const float s512 = 0.044194173824159216f; // 1/sqrt(512)
    // persistent grid: 256 blocks x 4 tiles = 1024 tiles (512 mt x 2 nt)
    mlp_gemm<0, 640><<<256, 1024, 0, stream>>>(XB, SCAL, W1t, s640, nullptr, H1, nullptr);
    mlp_gemm<0, 512><<<256, 1024, 0, stream>>>(H1, nullptr, W2t, s512, nullptr, H2, nullptr);
    mlp_gemm<1, 512><<<256, 1024, 0, stream>>>(H2, nullptr, W3t, s512, ENV, nullptr, out);
}